// Round 12
// baseline (458.926 us; speedup 1.0000x reference)
//
#include <hip/hip_runtime.h>

typedef __attribute__((ext_vector_type(8))) short bf16x8;
typedef __attribute__((ext_vector_type(4))) float f32x4;

__device__ inline unsigned short f2bf(float f) {
    unsigned u = __float_as_uint(f);
    unsigned r = (u + 0x7FFF + ((u >> 16) & 1)) >> 16;   // RNE
    return (unsigned short)r;
}
__device__ inline float bf2f(unsigned short h) { return __uint_as_float((unsigned)h << 16); }

// ---------------- CSR build ----------------
__global__ void degree_kernel(const int* __restrict__ dst, int* __restrict__ deg, int E) {
    int e = blockIdx.x * blockDim.x + threadIdx.x;
    if (e < E) atomicAdd(&deg[dst[e]], 1);
}

__global__ void scan_reduce(const int* __restrict__ deg, int* __restrict__ bsum, int N) {
    __shared__ int sd[256];
    int b = blockIdx.x, t = threadIdx.x;
    int base = b * 1024, s = 0;
    for (int i = t; i < 1024; i += 256) {
        int idx = base + i;
        s += (idx < N) ? deg[idx] : 0;
    }
    sd[t] = s; __syncthreads();
    for (int st = 128; st > 0; st >>= 1) {
        if (t < st) sd[t] += sd[t + st];
        __syncthreads();
    }
    if (t == 0) bsum[b] = sd[0];
}

__global__ void scan_bsum(int* __restrict__ bsum, int nb) {
    __shared__ int s[256];
    int t = threadIdx.x;
    int v = (t < nb) ? bsum[t] : 0;
    s[t] = v; __syncthreads();
    for (int st = 1; st < 256; st <<= 1) {
        int add = (t >= st) ? s[t - st] : 0;
        __syncthreads();
        s[t] += add;
        __syncthreads();
    }
    if (t < nb) bsum[t] = s[t] - v;
}

__global__ void scan_final(const int* __restrict__ deg, const int* __restrict__ bsum,
                           int* __restrict__ off, int* __restrict__ pos, int N, int E) {
    __shared__ int ts[256];
    int b = blockIdx.x, t = threadIdx.x, base = b * 1024;
    int v[4], s = 0;
    #pragma unroll
    for (int j = 0; j < 4; ++j) {
        int idx = base + t * 4 + j;
        v[j] = (idx < N) ? deg[idx] : 0;
        s += v[j];
    }
    ts[t] = s; __syncthreads();
    int mine = s;
    for (int st = 1; st < 256; st <<= 1) {
        int add = (t >= st) ? ts[t - st] : 0;
        __syncthreads();
        ts[t] += add;
        __syncthreads();
    }
    int ex = ts[t] - mine + bsum[b];
    #pragma unroll
    for (int j = 0; j < 4; ++j) {
        int idx = base + t * 4 + j;
        if (idx < N) { off[idx] = ex; pos[idx] = ex; }
        ex += v[j];
    }
    if (b == 0 && t == 0) off[N] = E;
}

__global__ void bucket_kernel(const int* __restrict__ src, const int* __restrict__ dst,
                              int* __restrict__ pos, int* __restrict__ eid, int E) {
    int e = blockIdx.x * blockDim.x + threadIdx.x;
    if (e < E) {
        int p = atomicAdd(&pos[dst[e]], 1);
        eid[p] = src[e];
    }
}

// ---------------- aggregate (mean) layer 0: 4 nodes/wave, 16 lanes/row ----------------
__global__ __launch_bounds__(256) void aggregate64p(
    const unsigned short* __restrict__ xhi, const int* __restrict__ eid,
    const int* __restrict__ off, unsigned short* __restrict__ aggp, int N)
{
    int t = threadIdx.x, wave = t >> 6, lane = t & 63;
    int grp = lane >> 4, l16 = lane & 15;
    int n = blockIdx.x * 16 + wave * 4 + grp;
    bool active = (n < N);
    int s0 = 0, s1 = 0;
    if (active) { s0 = off[n]; s1 = off[n + 1]; }
    float ax = 0.0f, ay = 0.0f, az = 0.0f, aw = 0.0f;
    int i = s0;
    for (; i + 3 < s1; i += 4) {
        ushort4 v[4];
        #pragma unroll
        for (int j = 0; j < 4; ++j)
            v[j] = *(const ushort4*)(xhi + (size_t)eid[i + j] * 64 + l16 * 4);
        #pragma unroll
        for (int j = 0; j < 4; ++j) {
            ax += bf2f(v[j].x); ay += bf2f(v[j].y);
            az += bf2f(v[j].z); aw += bf2f(v[j].w);
        }
    }
    for (; i < s1; ++i) {
        ushort4 v = *(const ushort4*)(xhi + (size_t)eid[i] * 64 + l16 * 4);
        ax += bf2f(v.x); ay += bf2f(v.y); az += bf2f(v.z); aw += bf2f(v.w);
    }
    if (!active) return;
    float inv = (s1 > s0) ? 1.0f / (float)(s1 - s0) : 0.0f;
    float m[4] = {ax * inv, ay * inv, az * inv, aw * inv};
    unsigned short hv[4], lv[4];
    #pragma unroll
    for (int j = 0; j < 4; ++j) {
        hv[j] = f2bf(m[j]);
        lv[j] = f2bf(m[j] - bf2f(hv[j]));
    }
    unsigned short* row = aggp + (size_t)n * 128;
    int base = (l16 >> 1) * 16 + (l16 & 1) * 4;
    *(ushort4*)&row[base]     = make_ushort4(hv[0], hv[1], hv[2], hv[3]);
    *(ushort4*)&row[base + 8] = make_ushort4(lv[0], lv[1], lv[2], lv[3]);
}

// ---------------- aggregate (mean) layer 1: 2 nodes/wave, 32 lanes/row ----------------
__global__ __launch_bounds__(256) void aggregate128p(
    const unsigned short* __restrict__ h_hi, const int* __restrict__ eid,
    const int* __restrict__ off, unsigned short* __restrict__ aggp, int N)
{
    int t = threadIdx.x, wave = t >> 6, lane = t & 63;
    int grp = lane >> 5, l32 = lane & 31;
    int n = blockIdx.x * 8 + wave * 2 + grp;
    bool active = (n < N);
    int s0 = 0, s1 = 0;
    if (active) { s0 = off[n]; s1 = off[n + 1]; }
    float ax = 0.0f, ay = 0.0f, az = 0.0f, aw = 0.0f;
    int i = s0;
    for (; i + 3 < s1; i += 4) {
        ushort4 v[4];
        #pragma unroll
        for (int j = 0; j < 4; ++j)
            v[j] = *(const ushort4*)(h_hi + (size_t)eid[i + j] * 128 + l32 * 4);
        #pragma unroll
        for (int j = 0; j < 4; ++j) {
            ax += bf2f(v[j].x); ay += bf2f(v[j].y);
            az += bf2f(v[j].z); aw += bf2f(v[j].w);
        }
    }
    for (; i < s1; ++i) {
        ushort4 v = *(const ushort4*)(h_hi + (size_t)eid[i] * 128 + l32 * 4);
        ax += bf2f(v.x); ay += bf2f(v.y); az += bf2f(v.z); aw += bf2f(v.w);
    }
    if (!active) return;
    float inv = (s1 > s0) ? 1.0f / (float)(s1 - s0) : 0.0f;
    float m[4] = {ax * inv, ay * inv, az * inv, aw * inv};
    unsigned short hv[4], lv[4];
    #pragma unroll
    for (int j = 0; j < 4; ++j) {
        hv[j] = f2bf(m[j]);
        lv[j] = f2bf(m[j] - bf2f(hv[j]));
    }
    unsigned short* row = aggp + (size_t)n * 256;
    int base = (l32 >> 1) * 16 + (l32 & 1) * 4;
    *(ushort4*)&row[base]     = make_ushort4(hv[0], hv[1], hv[2], hv[3]);
    *(ushort4*)&row[base + 8] = make_ushort4(lv[0], lv[1], lv[2], lv[3]);
}

// ---------------- split x -> packed groups + bf16-hi rows ----------------
__global__ void split_x(const float* __restrict__ in, unsigned short* __restrict__ outp,
                        unsigned short* __restrict__ outh, int ngroups) {
    int i = blockIdx.x * blockDim.x + threadIdx.x;
    if (i >= ngroups) return;
    float4 a = ((const float4*)in)[i * 2];
    float4 b = ((const float4*)in)[i * 2 + 1];
    float f[8] = {a.x, a.y, a.z, a.w, b.x, b.y, b.z, b.w};
    unsigned short hv[8], lv[8];
    #pragma unroll
    for (int j = 0; j < 8; ++j) {
        unsigned short hb = f2bf(f[j]);
        hv[j] = hb;
        lv[j] = f2bf(f[j] - bf2f(hb));
    }
    ushort4* dst = (ushort4*)(outp + (size_t)i * 16);
    dst[0] = make_ushort4(hv[0], hv[1], hv[2], hv[3]);
    dst[1] = make_ushort4(hv[4], hv[5], hv[6], hv[7]);
    dst[2] = make_ushort4(lv[0], lv[1], lv[2], lv[3]);
    dst[3] = make_ushort4(lv[4], lv[5], lv[6], lv[7]);
    ushort4* dh = (ushort4*)(outh + (size_t)i * 8);
    dh[0] = make_ushort4(hv[0], hv[1], hv[2], hv[3]);
    dh[1] = make_ushort4(hv[4], hv[5], hv[6], hv[7]);
}

// ---------------- all weight packs in one kernel ----------------
__device__ inline void pack16(unsigned short* outp, int k, int col, float v) {
    int c = k >> 5, ko = k & 31, q = ko >> 3, jj = ko & 7;
    int nt = col >> 4, r = col & 15;
    int base = ((c * 8 + nt) * 64 + (q * 16 + r)) * 16;
    unsigned short hb = f2bf(v);
    outp[base + jj] = hb;
    outp[base + 8 + jj] = f2bf(v - bf2f(hb));
}

__global__ void pack_weights(const float* __restrict__ Wl0, const float* __restrict__ Wr0,
                             const float* __restrict__ Wl1, const float* __restrict__ Wr1,
                             const float* __restrict__ W1,
                             unsigned short* __restrict__ w0p, unsigned short* __restrict__ wLp,
                             unsigned short* __restrict__ w1h) {
    int tid = blockIdx.x * blockDim.x + threadIdx.x;
    if (tid < 16384) {                       // layer0: K=128
        int k = tid >> 7, col = tid & 127;
        float v = (k < 64) ? Wl0[k * 128 + col] : Wr0[(k - 64) * 128 + col];
        pack16(w0p, k, col, v);
    } else if (tid < 49152) {                // layer1: K=256
        int t2 = tid - 16384;
        int k = t2 >> 7, col = t2 & 127;
        float v = (k < 128) ? Wl1[k * 128 + col] : Wr1[(k - 128) * 128 + col];
        pack16(wLp, k, col, v);
    } else if (tid < 86016) {                // W1: K=288, hi only
        int t2 = tid - 49152;
        int k = t2 >> 7, col = t2 & 127;
        int c = k >> 5, ko = k & 31, q = ko >> 3, jj = ko & 7;
        int nt = col >> 4, r = col & 15;
        w1h[((c * 8 + nt) * 64 + q * 16 + r) * 8 + jj] = f2bf(W1[t2]);
    }
}

// ---------------- SAGE layer GEMM: split-bf16 MFMA ----------------
template<int K0, int K1, bool RELU, bool XPACK>
__global__ __launch_bounds__(256) void mfma_layer(
    const unsigned short* __restrict__ Ap,
    const unsigned short* __restrict__ Xd,
    const unsigned short* __restrict__ Wp,
    const float* __restrict__ bias,
    unsigned short* __restrict__ outh,
    int N)
{
    __shared__ float buf[4][64 * 36];

    const int t = threadIdx.x, wave = t >> 6, lane = t & 63;
    const int l15 = lane & 15, quad = lane >> 4;
    const int n0 = blockIdx.x * 64;

    f32x4 acc[4][2] = {};

    int nodes[4];
    #pragma unroll
    for (int mt = 0; mt < 4; ++mt) {
        int node = n0 + mt * 16 + l15;
        nodes[mt] = (node < N) ? node : (N - 1);
    }

    #pragma unroll
    for (int c = 0; c < K0 / 32; ++c) {
        bf16x8 ah[4], al[4];
        #pragma unroll
        for (int mt = 0; mt < 4; ++mt) {
            const unsigned short* p = Ap + ((size_t)nodes[mt] * (K0 / 8) + c * 4 + quad) * 16;
            ah[mt] = *(const bf16x8*)p;
            al[mt] = *(const bf16x8*)(p + 8);
        }
        #pragma unroll
        for (int ntl = 0; ntl < 2; ++ntl) {
            const int nt = wave * 2 + ntl;
            const unsigned short* wp = Wp + ((size_t)(c * 8 + nt) * 64 + lane) * 16;
            bf16x8 bh = *(const bf16x8*)wp;
            bf16x8 bl = *(const bf16x8*)(wp + 8);
            #pragma unroll
            for (int mt = 0; mt < 4; ++mt) {
                acc[mt][ntl] = __builtin_amdgcn_mfma_f32_16x16x32_bf16(ah[mt], bh, acc[mt][ntl], 0, 0, 0);
                acc[mt][ntl] = __builtin_amdgcn_mfma_f32_16x16x32_bf16(ah[mt], bl, acc[mt][ntl], 0, 0, 0);
                acc[mt][ntl] = __builtin_amdgcn_mfma_f32_16x16x32_bf16(al[mt], bh, acc[mt][ntl], 0, 0, 0);
            }
        }
    }

    #pragma unroll
    for (int c = 0; c < K1 / 32; ++c) {
        const int cc = K0 / 32 + c;
        bf16x8 ah[4], al[4];
        #pragma unroll
        for (int mt = 0; mt < 4; ++mt) {
            if (XPACK) {
                const unsigned short* p = Xd + ((size_t)nodes[mt] * (K1 / 8) + c * 4 + quad) * 16;
                ah[mt] = *(const bf16x8*)p;
                al[mt] = *(const bf16x8*)(p + 8);
            } else {
                ah[mt] = *(const bf16x8*)(Xd + (size_t)nodes[mt] * K1 + c * 32 + quad * 8);
            }
        }
        #pragma unroll
        for (int ntl = 0; ntl < 2; ++ntl) {
            const int nt = wave * 2 + ntl;
            const unsigned short* wp = Wp + ((size_t)(cc * 8 + nt) * 64 + lane) * 16;
            bf16x8 bh = *(const bf16x8*)wp;
            bf16x8 bl = *(const bf16x8*)(wp + 8);
            #pragma unroll
            for (int mt = 0; mt < 4; ++mt) {
                acc[mt][ntl] = __builtin_amdgcn_mfma_f32_16x16x32_bf16(ah[mt], bh, acc[mt][ntl], 0, 0, 0);
                acc[mt][ntl] = __builtin_amdgcn_mfma_f32_16x16x32_bf16(ah[mt], bl, acc[mt][ntl], 0, 0, 0);
                if (XPACK)
                    acc[mt][ntl] = __builtin_amdgcn_mfma_f32_16x16x32_bf16(al[mt], bh, acc[mt][ntl], 0, 0, 0);
            }
        }
    }

    float bv[2];
    bv[0] = bias[wave * 32 + l15];
    bv[1] = bias[wave * 32 + 16 + l15];

    #pragma unroll
    for (int mt = 0; mt < 4; ++mt)
        #pragma unroll
        for (int ntl = 0; ntl < 2; ++ntl)
            #pragma unroll
            for (int reg = 0; reg < 4; ++reg) {
                int node_l = mt * 16 + quad * 4 + reg;
                int col_l  = ntl * 16 + l15;
                float v = acc[mt][ntl][reg] + bv[ntl];
                if (RELU) v = fmaxf(v, 0.0f);
                buf[wave][node_l * 36 + col_l] = v;
            }
    __syncthreads();

    #pragma unroll
    for (int it = 0; it < 4; ++it) {
        int idx = it * 64 + lane;
        int node_l = idx >> 2, g = idx & 3;
        float4 v0 = *(const float4*)&buf[wave][node_l * 36 + g * 8];
        float4 v1 = *(const float4*)&buf[wave][node_l * 36 + g * 8 + 4];
        float f[8] = {v0.x, v0.y, v0.z, v0.w, v1.x, v1.y, v1.z, v1.w};
        bf16x8 hvv;
        #pragma unroll
        for (int j = 0; j < 8; ++j) hvv[j] = (short)f2bf(f[j]);
        int node_g = n0 + node_l;
        if (node_g < N)
            *(bf16x8*)(outh + (size_t)node_g * 128 + wave * 32 + g * 8) = hvv;
    }
}

// ---------------- classify: LDS-staged B (52 pairs, 3 blocks/CU) + global FIFO tail ----
__global__ __launch_bounds__(256, 3) void classify_mfma(
    const unsigned short* __restrict__ h1h,
    const int* __restrict__ fsrc, const int* __restrict__ fdst,
    const float* __restrict__ eattr,
    const unsigned short* __restrict__ w1h,
    const float* __restrict__ b1, const float* __restrict__ W2, const float* __restrict__ b2,
    float* __restrict__ out, int Ef)
{
    __shared__ unsigned short wlds[52 * 512];   // 52 pairs x 1 KB = 53248 B -> 3 blocks/CU

    const int t = threadIdx.x;
    const int wave = t >> 6, lane = t & 63;
    const int l15 = lane & 15, quad = lane >> 4;
    const int e0 = blockIdx.x * 128;

    // stage first 52 B pairs into LDS (3328 uint4 = 13/thread)
    {
        const uint4* s4 = (const uint4*)w1h;
        uint4* d4 = (uint4*)wlds;
        #pragma unroll
        for (int i = 0; i < 13; ++i)
            d4[t + i * 256] = s4[t + i * 256];
    }

    // per-lane edge indices
    int nsrc[2], ndst[2];
    #pragma unroll
    for (int mt = 0; mt < 2; ++mt) {
        int e = e0 + wave * 32 + mt * 16 + l15;
        if (e >= Ef) e = Ef - 1;
        nsrc[mt] = fsrc[e];
        ndst[mt] = fdst[e];
    }

    // eattr loads (issued early)
    float4 ef0[2], ef1[2];
    #pragma unroll
    for (int mt = 0; mt < 2; ++mt) {
        int e = e0 + wave * 32 + mt * 16 + l15;
        if (e >= Ef) e = Ef - 1;
        const float* pe = eattr + (size_t)e * 32 + quad * 8;
        ef0[mt] = *(const float4*)pe;
        ef1[mt] = *(const float4*)(pe + 4);
    }

    // preload ALL h1 A fragments (16 gathers in flight)
    bf16x8 a[2][8];
    #pragma unroll
    for (int kc = 0; kc < 8; ++kc)
        #pragma unroll
        for (int mt = 0; mt < 2; ++mt) {
            int node = (kc < 4) ? nsrc[mt] : ndst[mt];
            a[mt][kc] = *(const bf16x8*)(h1h + (size_t)node * 128 + (kc & 3) * 32 + quad * 8);
        }

    // prime 4-deep global FIFO for tail pairs 52..55
    const unsigned short* wbase = w1h + (size_t)lane * 8;
    bf16x8 bg[4];
    #pragma unroll
    for (int i = 0; i < 4; ++i)
        bg[i] = *(const bf16x8*)(wbase + (size_t)(52 + i) * 512);

    // eattr -> bf16 fragments (chunk 8)
    bf16x8 a8[2];
    #pragma unroll
    for (int mt = 0; mt < 2; ++mt) {
        float fv[8] = {ef0[mt].x, ef0[mt].y, ef0[mt].z, ef0[mt].w,
                       ef1[mt].x, ef1[mt].y, ef1[mt].z, ef1[mt].w};
        #pragma unroll
        for (int j = 0; j < 8; ++j) a8[mt][j] = (short)f2bf(fv[j]);
    }

    __syncthreads();   // LDS B ready

    f32x4 acc[2][8] = {};

    #pragma unroll
    for (int p = 0; p < 72; ++p) {          // 9 chunks x 8 nt = 72 pairs (K=288)
        const int kc = p >> 3, nt = p & 7;
        bf16x8 bh;
        if (p < 52) {
            bh = *(const bf16x8*)(&wlds[p * 512 + lane * 8]);
        } else {
            bh = bg[p & 3];
            if (p + 4 < 72)
                bg[p & 3] = *(const bf16x8*)(wbase + (size_t)(p + 4) * 512);
        }
        bf16x8 a0 = (kc < 8) ? a[0][kc] : a8[0];
        bf16x8 a1 = (kc < 8) ? a[1][kc] : a8[1];
        acc[0][nt] = __builtin_amdgcn_mfma_f32_16x16x32_bf16(a0, bh, acc[0][nt], 0, 0, 0);
        acc[1][nt] = __builtin_amdgcn_mfma_f32_16x16x32_bf16(a1, bh, acc[1][nt], 0, 0, 0);
    }

    float b1v[8], w2v[8];
    #pragma unroll
    for (int nt = 0; nt < 8; ++nt) {
        b1v[nt] = b1[nt * 16 + l15];
        w2v[nt] = W2[nt * 16 + l15];
    }
    const float b2s = b2[0];

    #pragma unroll
    for (int mt = 0; mt < 2; ++mt) {
        #pragma unroll
        for (int reg = 0; reg < 4; ++reg) {
            float s = 0.0f;
            #pragma unroll
            for (int nt = 0; nt < 8; ++nt) {
                float v = acc[mt][nt][reg] + b1v[nt];
                s += fmaxf(v, 0.0f) * w2v[nt];
            }
            s += __shfl_xor(s, 1);
            s += __shfl_xor(s, 2);
            s += __shfl_xor(s, 4);
            s += __shfl_xor(s, 8);
            if (l15 == 0) {
                int e = e0 + wave * 32 + mt * 16 + quad * 4 + reg;
                if (e < Ef) out[e] = s + b2s;
            }
        }
    }
}

extern "C" void kernel_launch(void* const* d_in, const int* in_sizes, int n_in,
                              void* d_out, int out_size, void* d_ws, size_t ws_size,
                              hipStream_t stream) {
    const float* x     = (const float*)d_in[0];
    const int*   ei    = (const int*)d_in[1];
    const int*   fei   = (const int*)d_in[2];
    const float* eattr = (const float*)d_in[3];
    const float* Wl0   = (const float*)d_in[4];
    const float* bl0   = (const float*)d_in[5];
    const float* Wr0   = (const float*)d_in[6];
    const float* Wl1   = (const float*)d_in[7];
    const float* bl1   = (const float*)d_in[8];
    const float* Wr1   = (const float*)d_in[9];
    const float* W1    = (const float*)d_in[10];
    const float* b1    = (const float*)d_in[11];
    const float* W2    = (const float*)d_in[12];
    const float* b2    = (const float*)d_in[13];

    const int E  = in_sizes[1] / 2;
    const int Ef = in_sizes[2] / 2;
    const int N  = in_sizes[0] / 64;

    const int* src  = ei;
    const int* dst  = ei + E;
    const int* fsrc = fei;
    const int* fdst = fei + Ef;

    // workspace layout (units: floats)
    float* wsf = (float*)d_ws;
    size_t o = 0;
    int* deg  = (int*)(wsf + o); o += 131072;
    int* off  = (int*)(wsf + o); o += 131072;
    int* pos  = (int*)(wsf + o); o += 131072;
    int* bsum = (int*)(wsf + o); o += 256;
    int* eid  = (int*)(wsf + o); o += 1 << 20;
    unsigned short* w0p = (unsigned short*)(wsf + o); o += 16384;
    unsigned short* wLp = (unsigned short*)(wsf + o); o += 32768;
    unsigned short* w1h = (unsigned short*)(wsf + o); o += 18432;
    unsigned short* xp  = (unsigned short*)(wsf + o); o += (size_t)N * 64;   // packed x; later h_hi
    unsigned short* xhi = (unsigned short*)(wsf + o); o += (size_t)N * 32;   // bf16-hi x rows
    unsigned short* aggp= (unsigned short*)(wsf + o); o += (size_t)N * 128;  // packed agg (both layers)
    unsigned short* h1_hi=(unsigned short*)(wsf + o); o += (size_t)N * 64;   // bf16-hi h1 rows

    unsigned short* h_hi = xp;   // overlay: mfma_layer0 writes its own block's rows only
    float* out = (float*)d_out;

    const int nb = (N + 1023) / 1024;

    hipMemsetAsync(deg, 0, (size_t)N * 4, stream);
    degree_kernel<<<(E + 255) / 256, 256, 0, stream>>>(dst, deg, E);
    scan_reduce<<<nb, 256, 0, stream>>>(deg, bsum, N);
    scan_bsum<<<1, 256, 0, stream>>>(bsum, nb);
    scan_final<<<nb, 256, 0, stream>>>(deg, bsum, off, pos, N, E);
    bucket_kernel<<<(E + 255) / 256, 256, 0, stream>>>(src, dst, pos, eid, E);

    pack_weights<<<(86016 + 255) / 256, 256, 0, stream>>>(Wl0, Wr0, Wl1, Wr1, W1, w0p, wLp, w1h);

    split_x<<<((N * 8) + 255) / 256, 256, 0, stream>>>(x, xp, xhi, N * 8);

    aggregate64p<<<(N + 15) / 16, 256, 0, stream>>>(xhi, eid, off, aggp, N);
    mfma_layer<64, 64, true, true><<<(N + 63) / 64, 256, 0, stream>>>(
        aggp, xp, w0p, bl0, h_hi, N);

    aggregate128p<<<(N + 7) / 8, 256, 0, stream>>>(h_hi, eid, off, aggp, N);
    mfma_layer<128, 128, false, false><<<(N + 63) / 64, 256, 0, stream>>>(
        aggp, h_hi, wLp, bl1, h1_hi, N);

    classify_mfma<<<(Ef + 127) / 128, 256, 0, stream>>>(
        h1_hi, fsrc, fdst, eattr, w1h, b1, W2, b2, out, Ef);
}

// Round 13
// 454.932 us; speedup vs baseline: 1.0088x; 1.0088x over previous
//
#include <hip/hip_runtime.h>

typedef __attribute__((ext_vector_type(8))) short bf16x8;
typedef __attribute__((ext_vector_type(4))) float f32x4;

__device__ inline unsigned short f2bf(float f) {
    unsigned u = __float_as_uint(f);
    unsigned r = (u + 0x7FFF + ((u >> 16) & 1)) >> 16;   // RNE
    return (unsigned short)r;
}
__device__ inline float bf2f(unsigned short h) { return __uint_as_float((unsigned)h << 16); }

// ---------------- CSR build ----------------
__global__ void degree_kernel(const int* __restrict__ dst, int* __restrict__ deg, int E) {
    int e = blockIdx.x * blockDim.x + threadIdx.x;
    if (e < E) atomicAdd(&deg[dst[e]], 1);
}

__global__ void scan_reduce(const int* __restrict__ deg, int* __restrict__ bsum, int N) {
    __shared__ int sd[256];
    int b = blockIdx.x, t = threadIdx.x;
    int base = b * 1024, s = 0;
    for (int i = t; i < 1024; i += 256) {
        int idx = base + i;
        s += (idx < N) ? deg[idx] : 0;
    }
    sd[t] = s; __syncthreads();
    for (int st = 128; st > 0; st >>= 1) {
        if (t < st) sd[t] += sd[t + st];
        __syncthreads();
    }
    if (t == 0) bsum[b] = sd[0];
}

__global__ void scan_bsum(int* __restrict__ bsum, int nb) {
    __shared__ int s[256];
    int t = threadIdx.x;
    int v = (t < nb) ? bsum[t] : 0;
    s[t] = v; __syncthreads();
    for (int st = 1; st < 256; st <<= 1) {
        int add = (t >= st) ? s[t - st] : 0;
        __syncthreads();
        s[t] += add;
        __syncthreads();
    }
    if (t < nb) bsum[t] = s[t] - v;
}

__global__ void scan_final(const int* __restrict__ deg, const int* __restrict__ bsum,
                           int* __restrict__ off, int* __restrict__ pos, int N, int E) {
    __shared__ int ts[256];
    int b = blockIdx.x, t = threadIdx.x, base = b * 1024;
    int v[4], s = 0;
    #pragma unroll
    for (int j = 0; j < 4; ++j) {
        int idx = base + t * 4 + j;
        v[j] = (idx < N) ? deg[idx] : 0;
        s += v[j];
    }
    ts[t] = s; __syncthreads();
    int mine = s;
    for (int st = 1; st < 256; st <<= 1) {
        int add = (t >= st) ? ts[t - st] : 0;
        __syncthreads();
        ts[t] += add;
        __syncthreads();
    }
    int ex = ts[t] - mine + bsum[b];
    #pragma unroll
    for (int j = 0; j < 4; ++j) {
        int idx = base + t * 4 + j;
        if (idx < N) { off[idx] = ex; pos[idx] = ex; }
        ex += v[j];
    }
    if (b == 0 && t == 0) off[N] = E;
}

__global__ void bucket_kernel(const int* __restrict__ src, const int* __restrict__ dst,
                              int* __restrict__ pos, int* __restrict__ eid, int E) {
    int e = blockIdx.x * blockDim.x + threadIdx.x;
    if (e < E) {
        int p = atomicAdd(&pos[dst[e]], 1);
        eid[p] = src[e];
    }
}

// ---------------- aggregate (mean) layer 0: 4 nodes/wave, 16 lanes/row, 8-deep ----------
__global__ __launch_bounds__(256) void aggregate64p(
    const unsigned short* __restrict__ xhi, const int* __restrict__ eid,
    const int* __restrict__ off, unsigned short* __restrict__ aggp, int N)
{
    int t = threadIdx.x, wave = t >> 6, lane = t & 63;
    int grp = lane >> 4, l16 = lane & 15;
    int n = blockIdx.x * 16 + wave * 4 + grp;
    bool active = (n < N);
    int s0 = 0, s1 = 0;
    if (active) { s0 = off[n]; s1 = off[n + 1]; }
    float ax = 0.0f, ay = 0.0f, az = 0.0f, aw = 0.0f;
    int i = s0;
    for (; i + 7 < s1; i += 8) {
        ushort4 v[8];
        #pragma unroll
        for (int j = 0; j < 8; ++j)
            v[j] = *(const ushort4*)(xhi + (size_t)eid[i + j] * 64 + l16 * 4);
        #pragma unroll
        for (int j = 0; j < 8; ++j) {
            ax += bf2f(v[j].x); ay += bf2f(v[j].y);
            az += bf2f(v[j].z); aw += bf2f(v[j].w);
        }
    }
    for (; i < s1; ++i) {
        ushort4 v = *(const ushort4*)(xhi + (size_t)eid[i] * 64 + l16 * 4);
        ax += bf2f(v.x); ay += bf2f(v.y); az += bf2f(v.z); aw += bf2f(v.w);
    }
    if (!active) return;
    float inv = (s1 > s0) ? 1.0f / (float)(s1 - s0) : 0.0f;
    float m[4] = {ax * inv, ay * inv, az * inv, aw * inv};
    unsigned short hv[4], lv[4];
    #pragma unroll
    for (int j = 0; j < 4; ++j) {
        hv[j] = f2bf(m[j]);
        lv[j] = f2bf(m[j] - bf2f(hv[j]));
    }
    unsigned short* row = aggp + (size_t)n * 128;
    int base = (l16 >> 1) * 16 + (l16 & 1) * 4;
    *(ushort4*)&row[base]     = make_ushort4(hv[0], hv[1], hv[2], hv[3]);
    *(ushort4*)&row[base + 8] = make_ushort4(lv[0], lv[1], lv[2], lv[3]);
}

// ---------------- aggregate (mean) layer 1: 2 nodes/wave, 32 lanes/row, 8-deep ----------
__global__ __launch_bounds__(256) void aggregate128p(
    const unsigned short* __restrict__ h_hi, const int* __restrict__ eid,
    const int* __restrict__ off, unsigned short* __restrict__ aggp, int N)
{
    int t = threadIdx.x, wave = t >> 6, lane = t & 63;
    int grp = lane >> 5, l32 = lane & 31;
    int n = blockIdx.x * 8 + wave * 2 + grp;
    bool active = (n < N);
    int s0 = 0, s1 = 0;
    if (active) { s0 = off[n]; s1 = off[n + 1]; }
    float ax = 0.0f, ay = 0.0f, az = 0.0f, aw = 0.0f;
    int i = s0;
    for (; i + 7 < s1; i += 8) {
        ushort4 v[8];
        #pragma unroll
        for (int j = 0; j < 8; ++j)
            v[j] = *(const ushort4*)(h_hi + (size_t)eid[i + j] * 128 + l32 * 4);
        #pragma unroll
        for (int j = 0; j < 8; ++j) {
            ax += bf2f(v[j].x); ay += bf2f(v[j].y);
            az += bf2f(v[j].z); aw += bf2f(v[j].w);
        }
    }
    for (; i < s1; ++i) {
        ushort4 v = *(const ushort4*)(h_hi + (size_t)eid[i] * 128 + l32 * 4);
        ax += bf2f(v.x); ay += bf2f(v.y); az += bf2f(v.z); aw += bf2f(v.w);
    }
    if (!active) return;
    float inv = (s1 > s0) ? 1.0f / (float)(s1 - s0) : 0.0f;
    float m[4] = {ax * inv, ay * inv, az * inv, aw * inv};
    unsigned short hv[4], lv[4];
    #pragma unroll
    for (int j = 0; j < 4; ++j) {
        hv[j] = f2bf(m[j]);
        lv[j] = f2bf(m[j] - bf2f(hv[j]));
    }
    unsigned short* row = aggp + (size_t)n * 256;
    int base = (l32 >> 1) * 16 + (l32 & 1) * 4;
    *(ushort4*)&row[base]     = make_ushort4(hv[0], hv[1], hv[2], hv[3]);
    *(ushort4*)&row[base + 8] = make_ushort4(lv[0], lv[1], lv[2], lv[3]);
}

// ---------------- fused: split x (groups + hi rows) AND pack all weights ----------------
__device__ inline void pack16(unsigned short* outp, int k, int col, float v) {
    int c = k >> 5, ko = k & 31, q = ko >> 3, jj = ko & 7;
    int nt = col >> 4, r = col & 15;
    int base = ((c * 8 + nt) * 64 + (q * 16 + r)) * 16;
    unsigned short hb = f2bf(v);
    outp[base + jj] = hb;
    outp[base + 8 + jj] = f2bf(v - bf2f(hb));
}

__global__ void prep_kernel(const float* __restrict__ x,
                            unsigned short* __restrict__ xp, unsigned short* __restrict__ xhi,
                            int ngroups,
                            const float* __restrict__ Wl0, const float* __restrict__ Wr0,
                            const float* __restrict__ Wl1, const float* __restrict__ Wr1,
                            const float* __restrict__ W1,
                            unsigned short* __restrict__ w0p, unsigned short* __restrict__ wLp,
                            unsigned short* __restrict__ w1h) {
    int gid = blockIdx.x * blockDim.x + threadIdx.x;
    if (gid < ngroups) {
        int i = gid;
        float4 a = ((const float4*)x)[i * 2];
        float4 b = ((const float4*)x)[i * 2 + 1];
        float f[8] = {a.x, a.y, a.z, a.w, b.x, b.y, b.z, b.w};
        unsigned short hv[8], lv[8];
        #pragma unroll
        for (int j = 0; j < 8; ++j) {
            unsigned short hb = f2bf(f[j]);
            hv[j] = hb;
            lv[j] = f2bf(f[j] - bf2f(hb));
        }
        ushort4* dst = (ushort4*)(xp + (size_t)i * 16);
        dst[0] = make_ushort4(hv[0], hv[1], hv[2], hv[3]);
        dst[1] = make_ushort4(hv[4], hv[5], hv[6], hv[7]);
        dst[2] = make_ushort4(lv[0], lv[1], lv[2], lv[3]);
        dst[3] = make_ushort4(lv[4], lv[5], lv[6], lv[7]);
        ushort4* dh = (ushort4*)(xhi + (size_t)i * 8);
        dh[0] = make_ushort4(hv[0], hv[1], hv[2], hv[3]);
        dh[1] = make_ushort4(hv[4], hv[5], hv[6], hv[7]);
        return;
    }
    int tid = gid - ngroups;
    if (tid < 16384) {                       // layer0: K=128
        int k = tid >> 7, col = tid & 127;
        float v = (k < 64) ? Wl0[k * 128 + col] : Wr0[(k - 64) * 128 + col];
        pack16(w0p, k, col, v);
    } else if (tid < 49152) {                // layer1: K=256
        int t2 = tid - 16384;
        int k = t2 >> 7, col = t2 & 127;
        float v = (k < 128) ? Wl1[k * 128 + col] : Wr1[(k - 128) * 128 + col];
        pack16(wLp, k, col, v);
    } else if (tid < 86016) {                // W1: K=288, hi only
        int t2 = tid - 49152;
        int k = t2 >> 7, col = t2 & 127;
        int c = k >> 5, ko = k & 31, q = ko >> 3, jj = ko & 7;
        int nt = col >> 4, r = col & 15;
        w1h[((c * 8 + nt) * 64 + q * 16 + r) * 8 + jj] = f2bf(W1[t2]);
    }
}

// ---------------- SAGE layer GEMM: split-bf16 MFMA ----------------
template<int K0, int K1, bool RELU, bool XPACK>
__global__ __launch_bounds__(256) void mfma_layer(
    const unsigned short* __restrict__ Ap,
    const unsigned short* __restrict__ Xd,
    const unsigned short* __restrict__ Wp,
    const float* __restrict__ bias,
    unsigned short* __restrict__ outh,
    int N)
{
    __shared__ float buf[4][64 * 36];

    const int t = threadIdx.x, wave = t >> 6, lane = t & 63;
    const int l15 = lane & 15, quad = lane >> 4;
    const int n0 = blockIdx.x * 64;

    f32x4 acc[4][2] = {};

    int nodes[4];
    #pragma unroll
    for (int mt = 0; mt < 4; ++mt) {
        int node = n0 + mt * 16 + l15;
        nodes[mt] = (node < N) ? node : (N - 1);
    }

    #pragma unroll
    for (int c = 0; c < K0 / 32; ++c) {
        bf16x8 ah[4], al[4];
        #pragma unroll
        for (int mt = 0; mt < 4; ++mt) {
            const unsigned short* p = Ap + ((size_t)nodes[mt] * (K0 / 8) + c * 4 + quad) * 16;
            ah[mt] = *(const bf16x8*)p;
            al[mt] = *(const bf16x8*)(p + 8);
        }
        #pragma unroll
        for (int ntl = 0; ntl < 2; ++ntl) {
            const int nt = wave * 2 + ntl;
            const unsigned short* wp = Wp + ((size_t)(c * 8 + nt) * 64 + lane) * 16;
            bf16x8 bh = *(const bf16x8*)wp;
            bf16x8 bl = *(const bf16x8*)(wp + 8);
            #pragma unroll
            for (int mt = 0; mt < 4; ++mt) {
                acc[mt][ntl] = __builtin_amdgcn_mfma_f32_16x16x32_bf16(ah[mt], bh, acc[mt][ntl], 0, 0, 0);
                acc[mt][ntl] = __builtin_amdgcn_mfma_f32_16x16x32_bf16(ah[mt], bl, acc[mt][ntl], 0, 0, 0);
                acc[mt][ntl] = __builtin_amdgcn_mfma_f32_16x16x32_bf16(al[mt], bh, acc[mt][ntl], 0, 0, 0);
            }
        }
    }

    #pragma unroll
    for (int c = 0; c < K1 / 32; ++c) {
        const int cc = K0 / 32 + c;
        bf16x8 ah[4], al[4];
        #pragma unroll
        for (int mt = 0; mt < 4; ++mt) {
            if (XPACK) {
                const unsigned short* p = Xd + ((size_t)nodes[mt] * (K1 / 8) + c * 4 + quad) * 16;
                ah[mt] = *(const bf16x8*)p;
                al[mt] = *(const bf16x8*)(p + 8);
            } else {
                ah[mt] = *(const bf16x8*)(Xd + (size_t)nodes[mt] * K1 + c * 32 + quad * 8);
            }
        }
        #pragma unroll
        for (int ntl = 0; ntl < 2; ++ntl) {
            const int nt = wave * 2 + ntl;
            const unsigned short* wp = Wp + ((size_t)(cc * 8 + nt) * 64 + lane) * 16;
            bf16x8 bh = *(const bf16x8*)wp;
            bf16x8 bl = *(const bf16x8*)(wp + 8);
            #pragma unroll
            for (int mt = 0; mt < 4; ++mt) {
                acc[mt][ntl] = __builtin_amdgcn_mfma_f32_16x16x32_bf16(ah[mt], bh, acc[mt][ntl], 0, 0, 0);
                acc[mt][ntl] = __builtin_amdgcn_mfma_f32_16x16x32_bf16(ah[mt], bl, acc[mt][ntl], 0, 0, 0);
                if (XPACK)
                    acc[mt][ntl] = __builtin_amdgcn_mfma_f32_16x16x32_bf16(al[mt], bh, acc[mt][ntl], 0, 0, 0);
            }
        }
    }

    float bv[2];
    bv[0] = bias[wave * 32 + l15];
    bv[1] = bias[wave * 32 + 16 + l15];

    #pragma unroll
    for (int mt = 0; mt < 4; ++mt)
        #pragma unroll
        for (int ntl = 0; ntl < 2; ++ntl)
            #pragma unroll
            for (int reg = 0; reg < 4; ++reg) {
                int node_l = mt * 16 + quad * 4 + reg;
                int col_l  = ntl * 16 + l15;
                float v = acc[mt][ntl][reg] + bv[ntl];
                if (RELU) v = fmaxf(v, 0.0f);
                buf[wave][node_l * 36 + col_l] = v;
            }
    __syncthreads();

    #pragma unroll
    for (int it = 0; it < 4; ++it) {
        int idx = it * 64 + lane;
        int node_l = idx >> 2, g = idx & 3;
        float4 v0 = *(const float4*)&buf[wave][node_l * 36 + g * 8];
        float4 v1 = *(const float4*)&buf[wave][node_l * 36 + g * 8 + 4];
        float f[8] = {v0.x, v0.y, v0.z, v0.w, v1.x, v1.y, v1.z, v1.w};
        bf16x8 hvv;
        #pragma unroll
        for (int j = 0; j < 8; ++j) hvv[j] = (short)f2bf(f[j]);
        int node_g = n0 + node_l;
        if (node_g < N)
            *(bf16x8*)(outh + (size_t)node_g * 128 + wave * 32 + g * 8) = hvv;
    }
}

// ---------------- classify: LDS-staged B (60 pairs) + 12 preloaded tail (R11 config) ----
__global__ __launch_bounds__(256, 2) void classify_mfma(
    const unsigned short* __restrict__ h1h,
    const int* __restrict__ fsrc, const int* __restrict__ fdst,
    const float* __restrict__ eattr,
    const unsigned short* __restrict__ w1h,
    const float* __restrict__ b1, const float* __restrict__ W2, const float* __restrict__ b2,
    float* __restrict__ out, int Ef)
{
    __shared__ unsigned short wlds[60 * 512];   // 60 pairs x 1 KB = 61440 B

    const int t = threadIdx.x;
    const int wave = t >> 6, lane = t & 63;
    const int l15 = lane & 15, quad = lane >> 4;
    const int e0 = blockIdx.x * 128;

    // stage first 60 B pairs into LDS (3840 uint4 = 15/thread)
    {
        const uint4* s4 = (const uint4*)w1h;
        uint4* d4 = (uint4*)wlds;
        #pragma unroll
        for (int i = 0; i < 15; ++i)
            d4[t + i * 256] = s4[t + i * 256];
    }

    // per-lane edge indices
    int nsrc[2], ndst[2];
    #pragma unroll
    for (int mt = 0; mt < 2; ++mt) {
        int e = e0 + wave * 32 + mt * 16 + l15;
        if (e >= Ef) e = Ef - 1;
        nsrc[mt] = fsrc[e];
        ndst[mt] = fdst[e];
    }

    // eattr loads (issued early)
    float4 ef0[2], ef1[2];
    #pragma unroll
    for (int mt = 0; mt < 2; ++mt) {
        int e = e0 + wave * 32 + mt * 16 + l15;
        if (e >= Ef) e = Ef - 1;
        const float* pe = eattr + (size_t)e * 32 + quad * 8;
        ef0[mt] = *(const float4*)pe;
        ef1[mt] = *(const float4*)(pe + 4);
    }

    // preload ALL h1 A fragments (16 gathers in flight)
    bf16x8 a[2][8];
    #pragma unroll
    for (int kc = 0; kc < 8; ++kc)
        #pragma unroll
        for (int mt = 0; mt < 2; ++mt) {
            int node = (kc < 4) ? nsrc[mt] : ndst[mt];
            a[mt][kc] = *(const bf16x8*)(h1h + (size_t)node * 128 + (kc & 3) * 32 + quad * 8);
        }

    // preload global tail B pairs 60..71 entirely into registers
    bf16x8 bg[12];
    #pragma unroll
    for (int i = 0; i < 12; ++i)
        bg[i] = *(const bf16x8*)(w1h + (size_t)(60 + i) * 512 + lane * 8);

    // eattr -> bf16 fragments (chunk 8)
    bf16x8 a8[2];
    #pragma unroll
    for (int mt = 0; mt < 2; ++mt) {
        float fv[8] = {ef0[mt].x, ef0[mt].y, ef0[mt].z, ef0[mt].w,
                       ef1[mt].x, ef1[mt].y, ef1[mt].z, ef1[mt].w};
        #pragma unroll
        for (int j = 0; j < 8; ++j) a8[mt][j] = (short)f2bf(fv[j]);
    }

    __syncthreads();   // LDS B ready

    f32x4 acc[2][8] = {};

    #pragma unroll
    for (int p = 0; p < 72; ++p) {          // 9 chunks x 8 nt = 72 pairs (K=288)
        const int kc = p >> 3, nt = p & 7;
        bf16x8 bh = (p < 60) ? *(const bf16x8*)(&wlds[p * 512 + lane * 8]) : bg[p - 60];
        bf16x8 a0 = (kc < 8) ? a[0][kc] : a8[0];
        bf16x8 a1 = (kc < 8) ? a[1][kc] : a8[1];
        acc[0][nt] = __builtin_amdgcn_mfma_f32_16x16x32_bf16(a0, bh, acc[0][nt], 0, 0, 0);
        acc[1][nt] = __builtin_amdgcn_mfma_f32_16x16x32_bf16(a1, bh, acc[1][nt], 0, 0, 0);
    }

    float b1v[8], w2v[8];
    #pragma unroll
    for (int nt = 0; nt < 8; ++nt) {
        b1v[nt] = b1[nt * 16 + l15];
        w2v[nt] = W2[nt * 16 + l15];
    }
    const float b2s = b2[0];

    #pragma unroll
    for (int mt = 0; mt < 2; ++mt) {
        #pragma unroll
        for (int reg = 0; reg < 4; ++reg) {
            float s = 0.0f;
            #pragma unroll
            for (int nt = 0; nt < 8; ++nt) {
                float v = acc[mt][nt][reg] + b1v[nt];
                s += fmaxf(v, 0.0f) * w2v[nt];
            }
            s += __shfl_xor(s, 1);
            s += __shfl_xor(s, 2);
            s += __shfl_xor(s, 4);
            s += __shfl_xor(s, 8);
            if (l15 == 0) {
                int e = e0 + wave * 32 + mt * 16 + quad * 4 + reg;
                if (e < Ef) out[e] = s + b2s;
            }
        }
    }
}

extern "C" void kernel_launch(void* const* d_in, const int* in_sizes, int n_in,
                              void* d_out, int out_size, void* d_ws, size_t ws_size,
                              hipStream_t stream) {
    const float* x     = (const float*)d_in[0];
    const int*   ei    = (const int*)d_in[1];
    const int*   fei   = (const int*)d_in[2];
    const float* eattr = (const float*)d_in[3];
    const float* Wl0   = (const float*)d_in[4];
    const float* bl0   = (const float*)d_in[5];
    const float* Wr0   = (const float*)d_in[6];
    const float* Wl1   = (const float*)d_in[7];
    const float* bl1   = (const float*)d_in[8];
    const float* Wr1   = (const float*)d_in[9];
    const float* W1    = (const float*)d_in[10];
    const float* b1    = (const float*)d_in[11];
    const float* W2    = (const float*)d_in[12];
    const float* b2    = (const float*)d_in[13];

    const int E  = in_sizes[1] / 2;
    const int Ef = in_sizes[2] / 2;
    const int N  = in_sizes[0] / 64;

    const int* src  = ei;
    const int* dst  = ei + E;
    const int* fsrc = fei;
    const int* fdst = fei + Ef;

    // workspace layout (units: floats)
    float* wsf = (float*)d_ws;
    size_t o = 0;
    int* deg  = (int*)(wsf + o); o += 131072;
    int* off  = (int*)(wsf + o); o += 131072;
    int* pos  = (int*)(wsf + o); o += 131072;
    int* bsum = (int*)(wsf + o); o += 256;
    int* eid  = (int*)(wsf + o); o += 1 << 20;
    unsigned short* w0p = (unsigned short*)(wsf + o); o += 16384;
    unsigned short* wLp = (unsigned short*)(wsf + o); o += 32768;
    unsigned short* w1h = (unsigned short*)(wsf + o); o += 18432;
    unsigned short* xp  = (unsigned short*)(wsf + o); o += (size_t)N * 64;   // packed x; later h_hi
    unsigned short* xhi = (unsigned short*)(wsf + o); o += (size_t)N * 32;   // bf16-hi x rows
    unsigned short* aggp= (unsigned short*)(wsf + o); o += (size_t)N * 128;  // packed agg (both layers)
    unsigned short* h1_hi=(unsigned short*)(wsf + o); o += (size_t)N * 64;   // bf16-hi h1 rows

    unsigned short* h_hi = xp;   // overlay: mfma_layer0 writes its own block's rows only
    float* out = (float*)d_out;

    const int nb = (N + 1023) / 1024;
    const int ngroups = N * 8;

    hipMemsetAsync(deg, 0, (size_t)N * 4, stream);
    degree_kernel<<<(E + 255) / 256, 256, 0, stream>>>(dst, deg, E);
    scan_reduce<<<nb, 256, 0, stream>>>(deg, bsum, N);
    scan_bsum<<<1, 256, 0, stream>>>(bsum, nb);
    scan_final<<<nb, 256, 0, stream>>>(deg, bsum, off, pos, N, E);
    bucket_kernel<<<(E + 255) / 256, 256, 0, stream>>>(src, dst, pos, eid, E);

    prep_kernel<<<(ngroups + 86016 + 255) / 256, 256, 0, stream>>>(
        x, xp, xhi, ngroups, Wl0, Wr0, Wl1, Wr1, W1, w0p, wLp, w1h);

    aggregate64p<<<(N + 15) / 16, 256, 0, stream>>>(xhi, eid, off, aggp, N);
    mfma_layer<64, 64, true, true><<<(N + 63) / 64, 256, 0, stream>>>(
        aggp, xp, w0p, bl0, h_hi, N);

    aggregate128p<<<(N + 7) / 8, 256, 0, stream>>>(h_hi, eid, off, aggp, N);
    mfma_layer<128, 128, false, false><<<(N + 63) / 64, 256, 0, stream>>>(
        aggp, h_hi, wLp, bl1, h1_hi, N);

    classify_mfma<<<(Ef + 127) / 128, 256, 0, stream>>>(
        h1_hi, fsrc, fdst, eattr, w1h, b1, W2, b2, out, Ef);
}